// Round 14
// baseline (497.465 us; speedup 1.0000x reference)
//
#include <hip/hip_runtime.h>
#include <hip/hip_bf16.h>

// MeshEdgeBlock fused kernel for MI355X (gfx950).
// R8 (2nd resubmit; rounds 12-13 hit GPU-acquisition timeouts, never measured).
// Finer barrier granularity. R7 post-mortem: source-level ILP interleave
// regressed (287->300us, VGPR stayed 60 -- compiler rescheduled it away);
// VALUBusy 41->25 (rcp-SiLU worked) with no time gain => VALU not critical.
// Revert interleave; keep rcp-SiLU. Structural change: ET 64->32 with
// 4 waves/block. Per-wave work IDENTICAL to R6 (32 rows x 32 cols/wave);
// LDS 80->40 KB => 4 blocks/CU (was 2), barrier scope 4 waves (was 8):
// each __syncthreads drains 1/4 of resident waves instead of 1/2.
//
// Structure (1 block = 32 edges, 256 threads = 4 waves):
//   X[32x384] staged (as bf16) in LDS in MFMA A-fragment chunk layout.
//   For each of 4 N-chunks of H (128 cols): GEMM1 chunk (depth-2 B-prefetch)
//   -> SiLU -> LDS (double-buffered, 1 barrier/nc) -> GEMM2 accumulate.
//   Wave q: all 32 rows, cols q*32..+32 (2x2 16x16 MFMA tiles).
//   Epilogue: +b2, LayerNorm (shfl butterfly + LDS combine), +edge residual.

typedef __bf16 bf16;
typedef __bf16 bf16x8 __attribute__((ext_vector_type(8)));
typedef float f32x4 __attribute__((ext_vector_type(4)));

#define E_TOT 250000
#define N_NODES 100000
#define ET 32
#define NBLK ((E_TOT + ET - 1) / ET)  // 7813

// ---------------------------------------------------------------------------
// Prep: pack fp32 row-major weights into bf16 B-fragment layout.
//   W1 [384,512]: W1p[((kb*4+quad)*512 + n)*8 + j] = bf16(W1[(kb*32+quad*8+j)*512 + n])
//   W2 [512,128]: W2p[((kc*4+quad)*128 + n)*8 + j] = bf16(W2[(kc*32+quad*8+j)*128 + n])
// Lane reads are then a single contiguous bf16x8 (16 B) per fragment.
// ---------------------------------------------------------------------------
__global__ __launch_bounds__(256) void pack_weights(const float* __restrict__ W1,
                                                    const float* __restrict__ W2,
                                                    bf16* __restrict__ W1p,
                                                    bf16* __restrict__ W2p) {
  int tid = blockIdx.x * blockDim.x + threadIdx.x;
  if (tid < 384 * 512) {
    int k = tid >> 9;  // row of W1
    int n = tid & 511;
    int kb = k >> 5, quad = (k >> 3) & 3, j = k & 7;
    W1p[(((kb * 4 + quad) * 512) + n) * 8 + j] = (bf16)W1[tid];
  }
  if (tid < 512 * 128) {
    int k = tid >> 7;  // row of W2
    int n = tid & 127;
    int kc = k >> 5, quad = (k >> 3) & 3, j = k & 7;
    W2p[(((kc * 4 + quad) * 128) + n) * 8 + j] = (bf16)W2[tid];
  }
}

__global__ __launch_bounds__(256, 4)
void edge_mlp_kernel(const float* __restrict__ srcf,
                     const float* __restrict__ dstf,
                     const float* __restrict__ edgef,
                     const int* __restrict__ sidx,
                     const int* __restrict__ didx,
                     const bf16* __restrict__ W1p,  // packed B-frag layout
                     const bf16* __restrict__ W2p,  // packed B-frag layout
                     const float* __restrict__ b1p,
                     const float* __restrict__ b2p,
                     const float* __restrict__ gp,
                     const float* __restrict__ bp,
                     float* __restrict__ out) {
  // Xs: 24 chunks (mt*12+kb)*512 bf16, A-frag layout: elem(m,k) at
  //     ((k%32)>>3)*128 + (m%16)*8 + (k%8) within chunk.  24 KB.
  // Hs: 2 buffers x 8 chunks (mt*4+kb2)*512, same layout.  16 KB.
  __shared__ __align__(16) bf16 Xs[24 * 512];
  __shared__ __align__(16) bf16 Hs[2 * 8 * 512];

  const int tid = threadIdx.x;
  const int w = tid >> 6;     // wave 0..3
  const int lane = tid & 63;
  const int l15 = lane & 15;
  const int quad = lane >> 4; // 0..3
  const int q = w;            // n-quarter (cols q*32..q*32+31)
  const long base = (long)blockIdx.x * ET;

  // ---- stage X: wave w handles edge group mt=w&1 (16 edges), kb-half w>>1 ----
  {
    const int mt = w & 1;
    const int half = w >> 1;  // 0: kb 0..5, 1: kb 6..11
    int e = (int)base + mt * 16 + l15;
    int ec = e < E_TOT ? e : (E_TOT - 1);  // clamp tail (stores guarded later)
    int si = sidx[ec];
    int di = didx[ec];
    si = si < 0 ? 0 : (si >= N_NODES ? N_NODES - 1 : si);
    di = di < 0 ? 0 : (di >= N_NODES ? N_NODES - 1 : di);
    const float* rs = srcf + (long)si * 128;
    const float* rd = dstf + (long)di * 128;
    const float* re = edgef + (long)ec * 128;
#pragma unroll
    for (int kk = 0; kk < 6; ++kk) {
      int kb = half * 6 + kk;
      const float* rowp = (kb < 4) ? rs : ((kb < 8) ? rd : re);
      int off = ((kb & 3) << 5) + (quad << 3);  // (kb%4)*32 + quad*8
      float4 v0 = *(const float4*)(rowp + off);
      float4 v1 = *(const float4*)(rowp + off + 4);
      bf16x8 vb;
      vb[0] = (bf16)v0.x; vb[1] = (bf16)v0.y; vb[2] = (bf16)v0.z; vb[3] = (bf16)v0.w;
      vb[4] = (bf16)v1.x; vb[5] = (bf16)v1.y; vb[6] = (bf16)v1.z; vb[7] = (bf16)v1.w;
      // lane (quad*16+l15) holds elems (m=l15, k%32=quad*8..+7): pos=lane*8
      *(bf16x8*)(&Xs[(mt * 12 + kb) * 512 + lane * 8]) = vb;
    }
  }

  // per-lane fixed epilogue columns: n2 = q*32 + t*16 + l15
  float b2v[2], gv[2], bv[2];
#pragma unroll
  for (int t = 0; t < 2; ++t) {
    int n2 = q * 32 + t * 16 + l15;
    b2v[t] = b2p[n2];
    gv[t] = gp[n2];
    bv[t] = bp[n2];
  }

  f32x4 acc2[2][2];
#pragma unroll
  for (int i = 0; i < 2; ++i)
#pragma unroll
    for (int t = 0; t < 2; ++t)
      acc2[i][t] = (f32x4){0.f, 0.f, 0.f, 0.f};

  __syncthreads();

  // ---- main loop: 4 chunks of 128 H-columns ----
  for (int nc = 0; nc < 4; ++nc) {
    bf16* hbuf = &Hs[(nc & 1) * 8 * 512];  // double-buffered H chunk

    // GEMM1 chunk: Hc[32,128] = X[32,384] @ W1[:, nc*128..]
    f32x4 acc1[2][2];
#pragma unroll
    for (int i = 0; i < 2; ++i)
#pragma unroll
      for (int t = 0; t < 2; ++t)
        acc1[i][t] = (f32x4){0.f, 0.f, 0.f, 0.f};

    float b1v[2];
#pragma unroll
    for (int t = 0; t < 2; ++t)
      b1v[t] = b1p[nc * 128 + q * 32 + t * 16 + l15];

    // depth-2 rotating B-frag prefetch: bB[kb&1] holds frags for step kb.
    bf16x8 bB[2][2];
#pragma unroll
    for (int p = 0; p < 2; ++p) {
      const bf16* wp = W1p + (((long)(p * 4 + quad) * 512) + nc * 128 + q * 32) * 8;
      bB[p][0] = *(const bf16x8*)(wp + l15 * 8);
      bB[p][1] = *(const bf16x8*)(wp + (16 + l15) * 8);
    }

#pragma unroll
    for (int kb = 0; kb < 12; ++kb) {
      bf16x8 a[2];
#pragma unroll
      for (int i = 0; i < 2; ++i)
        a[i] = *(const bf16x8*)(&Xs[(i * 12 + kb) * 512 + lane * 8]);
#pragma unroll
      for (int i = 0; i < 2; ++i)
#pragma unroll
        for (int t = 0; t < 2; ++t)
          acc1[i][t] = __builtin_amdgcn_mfma_f32_16x16x32_bf16(a[i], bB[kb & 1][t],
                                                              acc1[i][t], 0, 0, 0);
      if (kb < 10) {  // prefetch step kb+2 into the slot just consumed
        const bf16* wp =
            W1p + (((long)((kb + 2) * 4 + quad) * 512) + nc * 128 + q * 32) * 8;
        bB[kb & 1][0] = *(const bf16x8*)(wp + l15 * 8);
        bB[kb & 1][1] = *(const bf16x8*)(wp + (16 + l15) * 8);
      }
    }

    // bias + SiLU (rcp) + scatter into hbuf A-frag layout.
    // D layout: row m%16 = quad*4+r, col k2%32 = t*16+l15 (kb2 chunk = q).
    // Safe without a pre-barrier: this nc writes buf (nc&1); concurrent
    // laggard waves read buf ((nc-1)&1) in their GEMM2.
#pragma unroll
    for (int i = 0; i < 2; ++i)
#pragma unroll
      for (int t = 0; t < 2; ++t) {
        int pos0 = ((t * 2 + (l15 >> 3)) * 128) + (quad * 4) * 8 + (l15 & 7);
        bf16* hp = &hbuf[(i * 4 + q) * 512 + pos0];
#pragma unroll
        for (int r = 0; r < 4; ++r) {
          float vv = acc1[i][t][r] + b1v[t];
          float s = vv * __builtin_amdgcn_rcpf(1.0f + __expf(-vv));
          hp[r * 8] = (bf16)s;
        }
      }
    __syncthreads();  // hbuf fully written before GEMM2 reads it

    // GEMM2 partial: Y += Hc[32,128] @ W2[nc*128.., :]
    // depth-2 rotating B-frag prefetch, same pattern as GEMM1.
    bf16x8 bC[2][2];
#pragma unroll
    for (int p = 0; p < 2; ++p) {
      const bf16* wp =
          W2p + (((long)((nc * 4 + p) * 4 + quad) * 128) + q * 32) * 8;
      bC[p][0] = *(const bf16x8*)(wp + l15 * 8);
      bC[p][1] = *(const bf16x8*)(wp + (16 + l15) * 8);
    }

#pragma unroll
    for (int kb2 = 0; kb2 < 4; ++kb2) {
      bf16x8 a[2];
#pragma unroll
      for (int i = 0; i < 2; ++i)
        a[i] = *(const bf16x8*)(&hbuf[(i * 4 + kb2) * 512 + lane * 8]);
#pragma unroll
      for (int i = 0; i < 2; ++i)
#pragma unroll
        for (int t = 0; t < 2; ++t)
          acc2[i][t] = __builtin_amdgcn_mfma_f32_16x16x32_bf16(a[i], bC[kb2 & 1][t],
                                                              acc2[i][t], 0, 0, 0);
      if (kb2 < 2) {  // prefetch step kb2+2
        const bf16* wp =
            W2p + (((long)((nc * 4 + kb2 + 2) * 4 + quad) * 128) + q * 32) * 8;
        bC[kb2 & 1][0] = *(const bf16x8*)(wp + l15 * 8);
        bC[kb2 & 1][1] = *(const bf16x8*)(wp + (16 + l15) * 8);
      }
    }
    // no trailing barrier: next nc's GEMM1 touches only Xs + registers, and
    // its scatter targets the OTHER H buffer; the scatter->read barrier above
    // orders buffer reuse two nc's apart.
  }

  __syncthreads();  // all GEMM2 done; Hs reusable as LN scratch

  // ---- LayerNorm (32 rows) ----
  float* psum = (float*)Hs;      // [32][4]
  float* psq = psum + 128;       // [32][4]
  float* pmu = psq + 128;        // [32]
  float* prs = pmu + 32;         // [32]

#pragma unroll
  for (int i = 0; i < 2; ++i) {
#pragma unroll
    for (int r = 0; r < 4; ++r) {
      float v0 = acc2[i][0][r] + b2v[0];
      float v1 = acc2[i][1][r] + b2v[1];
      float s = v0 + v1;
      float ss = v0 * v0 + v1 * v1;
      // butterfly within 16-lane group -> sum of this wave's 32 cols per row
#pragma unroll
      for (int mk = 8; mk >= 1; mk >>= 1) {
        s += __shfl_xor(s, mk, 64);
        ss += __shfl_xor(ss, mk, 64);
      }
      if (l15 == 0) {
        int row = i * 16 + quad * 4 + r;
        psum[row * 4 + q] = s;
        psq[row * 4 + q] = ss;
      }
    }
  }
  __syncthreads();
  if (tid < 32) {
    float s = psum[tid * 4] + psum[tid * 4 + 1] + psum[tid * 4 + 2] + psum[tid * 4 + 3];
    float ss = psq[tid * 4] + psq[tid * 4 + 1] + psq[tid * 4 + 2] + psq[tid * 4 + 3];
    float mu = s * (1.0f / 128.0f);
    float var = fmaxf(ss * (1.0f / 128.0f) - mu * mu, 0.0f);  // cancellation-safe
    pmu[tid] = mu;
    prs[tid] = rsqrtf(var + 1e-5f);
  }
  __syncthreads();

  // ---- normalize + gamma/beta + edge residual (from Xs) + store ----
#pragma unroll
  for (int i = 0; i < 2; ++i) {
#pragma unroll
    for (int r = 0; r < 4; ++r) {
      int m = i * 16 + quad * 4 + r;
      long e = base + m;
      if (e >= E_TOT) continue;
      float mu = pmu[m];
      float rsg = prs[m];
#pragma unroll
      for (int t = 0; t < 2; ++t) {
        int n2 = q * 32 + t * 16 + l15;
        float v = acc2[i][t][r] + b2v[t];
        int posE = ((t * 2 + (l15 >> 3)) * 128) + (quad * 4 + r) * 8 + (l15 & 7);
        float ev = (float)Xs[(i * 12 + 8 + q) * 512 + posE];
        float y = (v - mu) * rsg * gv[t] + bv[t] + ev;
        out[e * 128 + n2] = y;
      }
    }
  }
}

extern "C" void kernel_launch(void* const* d_in, const int* in_sizes, int n_in,
                              void* d_out, int out_size, void* d_ws, size_t ws_size,
                              hipStream_t stream) {
  const float* srcf = (const float*)d_in[0];
  const float* dstf = (const float*)d_in[1];
  const float* edgef = (const float*)d_in[2];
  const int* sidx = (const int*)d_in[3];
  const int* didx = (const int*)d_in[4];
  const float* W1 = (const float*)d_in[5];
  const float* b1 = (const float*)d_in[6];
  const float* W2 = (const float*)d_in[7];
  const float* b2 = (const float*)d_in[8];
  const float* g = (const float*)d_in[9];
  const float* be = (const float*)d_in[10];
  float* out = (float*)d_out;

  // Workspace: W1p (384 KB bf16) then W2p (128 KB bf16).
  bf16* W1p = (bf16*)d_ws;
  bf16* W2p = W1p + 384 * 512;

  // Pack weights into MFMA B-fragment layout (cheap: ~1 MB read, 512 KB write).
  pack_weights<<<(384 * 512 + 255) / 256, 256, 0, stream>>>(W1, W2, W1p, W2p);

  edge_mlp_kernel<<<NBLK, 256, 0, stream>>>(srcf, dstf, edgef, sidx, didx,
                                            W1p, W2p, b1, b2, g, be, out);
}

// Round 17
// 486.966 us; speedup vs baseline: 1.0216x; 1.0216x over previous
//
#include <hip/hip_runtime.h>
#include <hip/hip_bf16.h>

// MeshEdgeBlock fused kernel for MI355X (gfx950).
// R9 (2nd resubmit; rounds 15-16 hit GPU-acquisition timeouts, never measured).
// Non-draining barriers. R8 (ET=32) falsified barrier-SCOPE theory
// (315us, regression; both R6/R8 are 16 waves/CU). Stacked-floors model:
// MFMA 52 + L2-Bfrags 116 + LDS 58 + HBM 60 ~= 286us = measured 287 (R6):
// phases serialize per-wave. Root cause of the serialization at barriers:
// __syncthreads emits s_waitcnt vmcnt(0) -- every barrier DRAINS in-flight
// weight loads (this also explains R7's hoisted-preload regression).
// Fix (guide T4): main-loop barriers become {s_waitcnt lgkmcnt(0); raw
// s_barrier} -- LDS ordering preserved, global weight loads (read-only,
// race-free) stay in flight across barriers. GEMM2's bC preloads hoisted
// above the pre-scatter barrier so they complete under scatter+barrier.
// Base: R6 geometry (ET=64, 8 waves, 80KB LDS, 2 blocks/CU) + rcp-SiLU.

typedef __bf16 bf16;
typedef __bf16 bf16x8 __attribute__((ext_vector_type(8)));
typedef float f32x4 __attribute__((ext_vector_type(4)));

#define E_TOT 250000
#define N_NODES 100000
#define ET 64
#define NBLK ((E_TOT + ET - 1) / ET)  // 3907

// lgkm-only barrier: orders LDS traffic without draining vmcnt.
#define SOFT_BARRIER()                                   \
  do {                                                   \
    asm volatile("s_waitcnt lgkmcnt(0)" ::: "memory");   \
    __builtin_amdgcn_s_barrier();                        \
    __builtin_amdgcn_sched_barrier(0);                   \
  } while (0)

// ---------------------------------------------------------------------------
// Prep: pack fp32 row-major weights into bf16 B-fragment layout.
//   W1 [384,512]: W1p[((kb*4+quad)*512 + n)*8 + j] = bf16(W1[(kb*32+quad*8+j)*512 + n])
//   W2 [512,128]: W2p[((kc*4+quad)*128 + n)*8 + j] = bf16(W2[(kc*32+quad*8+j)*128 + n])
// Lane reads are then a single contiguous bf16x8 (16 B) per fragment.
// ---------------------------------------------------------------------------
__global__ __launch_bounds__(256) void pack_weights(const float* __restrict__ W1,
                                                    const float* __restrict__ W2,
                                                    bf16* __restrict__ W1p,
                                                    bf16* __restrict__ W2p) {
  int tid = blockIdx.x * blockDim.x + threadIdx.x;
  if (tid < 384 * 512) {
    int k = tid >> 9;  // row of W1
    int n = tid & 511;
    int kb = k >> 5, quad = (k >> 3) & 3, j = k & 7;
    W1p[(((kb * 4 + quad) * 512) + n) * 8 + j] = (bf16)W1[tid];
  }
  if (tid < 512 * 128) {
    int k = tid >> 7;  // row of W2
    int n = tid & 127;
    int kc = k >> 5, quad = (k >> 3) & 3, j = k & 7;
    W2p[(((kc * 4 + quad) * 128) + n) * 8 + j] = (bf16)W2[tid];
  }
}

__global__ __launch_bounds__(512, 4)
void edge_mlp_kernel(const float* __restrict__ srcf,
                     const float* __restrict__ dstf,
                     const float* __restrict__ edgef,
                     const int* __restrict__ sidx,
                     const int* __restrict__ didx,
                     const bf16* __restrict__ W1p,  // packed B-frag layout
                     const bf16* __restrict__ W2p,  // packed B-frag layout
                     const float* __restrict__ b1p,
                     const float* __restrict__ b2p,
                     const float* __restrict__ gp,
                     const float* __restrict__ bp,
                     float* __restrict__ out) {
  // Xs: 48 chunks (mt*12+kb)*512 bf16, A-frag layout: elem(m,k) at
  //     ((k%32)>>3)*128 + (m%16)*8 + (k%8) within chunk.  48 KB.
  // Hs: 2 buffers x 16 chunks (mt*4+kb2)*512, same layout. 32 KB.
  __shared__ __align__(16) bf16 Xs[48 * 512];
  __shared__ __align__(16) bf16 Hs[2 * 16 * 512];

  const int tid = threadIdx.x;
  const int w = tid >> 6;     // wave 0..7
  const int lane = tid & 63;
  const int l15 = lane & 15;
  const int quad = lane >> 4; // 0..3
  const int h = w >> 2;       // m-half (rows h*32..h*32+31)
  const int q = w & 3;        // n-quarter (cols q*32..q*32+31)
  const long base = (long)blockIdx.x * ET;

  // ---- stage X: wave w handles edge group mt=w&3 (16 edges), kb-half w>>2 ----
  {
    const int mt = w & 3;
    const int half = w >> 2;  // 0: kb 0..5, 1: kb 6..11
    int e = (int)base + mt * 16 + l15;
    int ec = e < E_TOT ? e : (E_TOT - 1);  // clamp tail (stores guarded later)
    int si = sidx[ec];
    int di = didx[ec];
    si = si < 0 ? 0 : (si >= N_NODES ? N_NODES - 1 : si);
    di = di < 0 ? 0 : (di >= N_NODES ? N_NODES - 1 : di);
    const float* rs = srcf + (long)si * 128;
    const float* rd = dstf + (long)di * 128;
    const float* re = edgef + (long)ec * 128;
#pragma unroll
    for (int kk = 0; kk < 6; ++kk) {
      int kb = half * 6 + kk;
      const float* rowp = (kb < 4) ? rs : ((kb < 8) ? rd : re);
      int off = ((kb & 3) << 5) + (quad << 3);  // (kb%4)*32 + quad*8
      float4 v0 = *(const float4*)(rowp + off);
      float4 v1 = *(const float4*)(rowp + off + 4);
      bf16x8 vb;
      vb[0] = (bf16)v0.x; vb[1] = (bf16)v0.y; vb[2] = (bf16)v0.z; vb[3] = (bf16)v0.w;
      vb[4] = (bf16)v1.x; vb[5] = (bf16)v1.y; vb[6] = (bf16)v1.z; vb[7] = (bf16)v1.w;
      // lane (quad*16+l15) holds elems (m=l15, k%32=quad*8..+7): pos=lane*8
      *(bf16x8*)(&Xs[(mt * 12 + kb) * 512 + lane * 8]) = vb;
    }
  }

  // per-lane fixed epilogue columns: n2 = q*32 + t*16 + l15
  float b2v[2], gv[2], bv[2];
#pragma unroll
  for (int t = 0; t < 2; ++t) {
    int n2 = q * 32 + t * 16 + l15;
    b2v[t] = b2p[n2];
    gv[t] = gp[n2];
    bv[t] = bp[n2];
  }

  f32x4 acc2[2][2];
#pragma unroll
  for (int i = 0; i < 2; ++i)
#pragma unroll
    for (int t = 0; t < 2; ++t)
      acc2[i][t] = (f32x4){0.f, 0.f, 0.f, 0.f};

  __syncthreads();  // Xs staged (full drain ok: once per block)

  // ---- main loop: 4 chunks of 128 H-columns ----
  for (int nc = 0; nc < 4; ++nc) {
    bf16* hbuf = &Hs[(nc & 1) * 16 * 512];  // double-buffered H chunk

    // GEMM1 chunk: Hc[64,128] = X[64,384] @ W1[:, nc*128..]
    f32x4 acc1[2][2];
#pragma unroll
    for (int i = 0; i < 2; ++i)
#pragma unroll
      for (int t = 0; t < 2; ++t)
        acc1[i][t] = (f32x4){0.f, 0.f, 0.f, 0.f};

    float b1v[2];
#pragma unroll
    for (int t = 0; t < 2; ++t)
      b1v[t] = b1p[nc * 128 + q * 32 + t * 16 + l15];

    // depth-2 rotating B-frag prefetch: bB[kb&1] holds frags for step kb.
    bf16x8 bB[2][2];
#pragma unroll
    for (int p = 0; p < 2; ++p) {
      const bf16* wp = W1p + (((long)(p * 4 + quad) * 512) + nc * 128 + q * 32) * 8;
      bB[p][0] = *(const bf16x8*)(wp + l15 * 8);
      bB[p][1] = *(const bf16x8*)(wp + (16 + l15) * 8);
    }

#pragma unroll
    for (int kb = 0; kb < 12; ++kb) {
      bf16x8 a[2];
#pragma unroll
      for (int i = 0; i < 2; ++i)
        a[i] = *(const bf16x8*)(&Xs[((h * 2 + i) * 12 + kb) * 512 + lane * 8]);
#pragma unroll
      for (int i = 0; i < 2; ++i)
#pragma unroll
        for (int t = 0; t < 2; ++t)
          acc1[i][t] = __builtin_amdgcn_mfma_f32_16x16x32_bf16(a[i], bB[kb & 1][t],
                                                              acc1[i][t], 0, 0, 0);
      if (kb < 10) {  // prefetch step kb+2 into the slot just consumed
        const bf16* wp =
            W1p + (((long)((kb + 2) * 4 + quad) * 512) + nc * 128 + q * 32) * 8;
        bB[kb & 1][0] = *(const bf16x8*)(wp + l15 * 8);
        bB[kb & 1][1] = *(const bf16x8*)(wp + (16 + l15) * 8);
      }
    }

    // GEMM2 B-frag preloads issued HERE: they stay in flight across the
    // soft barriers + scatter below (no vmcnt(0) drain anymore).
    bf16x8 bC[2][2];
#pragma unroll
    for (int p = 0; p < 2; ++p) {
      const bf16* wp =
          W2p + (((long)((nc * 4 + p) * 4 + quad) * 128) + q * 32) * 8;
      bC[p][0] = *(const bf16x8*)(wp + l15 * 8);
      bC[p][1] = *(const bf16x8*)(wp + (16 + l15) * 8);
    }

    SOFT_BARRIER();  // prev GEMM2 readers done before hbuf overwrite

    // bias + SiLU (rcp) + scatter into hbuf A-frag layout.
    // D layout: row m%16 = quad*4+r, col k2%32 = t*16+l15 (kb2 chunk = q).
#pragma unroll
    for (int i = 0; i < 2; ++i)
#pragma unroll
      for (int t = 0; t < 2; ++t) {
        int pos0 = ((t * 2 + (l15 >> 3)) * 128) + (quad * 4) * 8 + (l15 & 7);
        bf16* hp = &hbuf[((h * 2 + i) * 4 + q) * 512 + pos0];
#pragma unroll
        for (int r = 0; r < 4; ++r) {
          float vv = acc1[i][t][r] + b1v[t];
          float s = vv * __builtin_amdgcn_rcpf(1.0f + __expf(-vv));
          hp[r * 8] = (bf16)s;
        }
      }

    SOFT_BARRIER();  // hbuf fully written (lgkmcnt(0) orders the ds_writes)

    // GEMM2 partial: Y += Hc[64,128] @ W2[nc*128.., :]
#pragma unroll
    for (int kb2 = 0; kb2 < 4; ++kb2) {
      bf16x8 a[2];
#pragma unroll
      for (int i = 0; i < 2; ++i)
        a[i] = *(const bf16x8*)(&hbuf[((h * 2 + i) * 4 + kb2) * 512 + lane * 8]);
#pragma unroll
      for (int i = 0; i < 2; ++i)
#pragma unroll
        for (int t = 0; t < 2; ++t)
          acc2[i][t] = __builtin_amdgcn_mfma_f32_16x16x32_bf16(a[i], bC[kb2 & 1][t],
                                                              acc2[i][t], 0, 0, 0);
      if (kb2 < 2) {  // prefetch step kb2+2
        const bf16* wp =
            W2p + (((long)((nc * 4 + kb2 + 2) * 4 + quad) * 128) + q * 32) * 8;
        bC[kb2 & 1][0] = *(const bf16x8*)(wp + l15 * 8);
        bC[kb2 & 1][1] = *(const bf16x8*)(wp + (16 + l15) * 8);
      }
    }
  }

  __syncthreads();  // all GEMM2 done; Hs reusable as LN scratch (full drain ok)

  // ---- LayerNorm (64 rows) ----
  float* psum = (float*)Hs;      // [64][4]
  float* psq = psum + 256;       // [64][4]
  float* pmu = psq + 256;        // [64]
  float* prs = pmu + 64;         // [64]

#pragma unroll
  for (int i = 0; i < 2; ++i) {
#pragma unroll
    for (int r = 0; r < 4; ++r) {
      float v0 = acc2[i][0][r] + b2v[0];
      float v1 = acc2[i][1][r] + b2v[1];
      float s = v0 + v1;
      float ss = v0 * v0 + v1 * v1;
      // butterfly within 16-lane group -> sum of this wave's 32 cols per row
#pragma unroll
      for (int mk = 8; mk >= 1; mk >>= 1) {
        s += __shfl_xor(s, mk, 64);
        ss += __shfl_xor(ss, mk, 64);
      }
      if (l15 == 0) {
        int row = (h * 2 + i) * 16 + quad * 4 + r;
        psum[row * 4 + q] = s;
        psq[row * 4 + q] = ss;
      }
    }
  }
  __syncthreads();
  if (tid < 64) {
    float s = psum[tid * 4] + psum[tid * 4 + 1] + psum[tid * 4 + 2] + psum[tid * 4 + 3];
    float ss = psq[tid * 4] + psq[tid * 4 + 1] + psq[tid * 4 + 2] + psq[tid * 4 + 3];
    float mu = s * (1.0f / 128.0f);
    float var = fmaxf(ss * (1.0f / 128.0f) - mu * mu, 0.0f);  // cancellation-safe
    pmu[tid] = mu;
    prs[tid] = rsqrtf(var + 1e-5f);
  }
  __syncthreads();

  // ---- normalize + gamma/beta + edge residual (from Xs) + store ----
#pragma unroll
  for (int i = 0; i < 2; ++i) {
#pragma unroll
    for (int r = 0; r < 4; ++r) {
      int m = (h * 2 + i) * 16 + quad * 4 + r;
      long e = base + m;
      if (e >= E_TOT) continue;
      float mu = pmu[m];
      float rsg = prs[m];
#pragma unroll
      for (int t = 0; t < 2; ++t) {
        int n2 = q * 32 + t * 16 + l15;
        float v = acc2[i][t][r] + b2v[t];
        int posE = ((t * 2 + (l15 >> 3)) * 128) + (quad * 4 + r) * 8 + (l15 & 7);
        float ev = (float)Xs[((h * 2 + i) * 12 + 8 + q) * 512 + posE];
        float y = (v - mu) * rsg * gv[t] + bv[t] + ev;
        out[e * 128 + n2] = y;
      }
    }
  }
}

extern "C" void kernel_launch(void* const* d_in, const int* in_sizes, int n_in,
                              void* d_out, int out_size, void* d_ws, size_t ws_size,
                              hipStream_t stream) {
  const float* srcf = (const float*)d_in[0];
  const float* dstf = (const float*)d_in[1];
  const float* edgef = (const float*)d_in[2];
  const int* sidx = (const int*)d_in[3];
  const int* didx = (const int*)d_in[4];
  const float* W1 = (const float*)d_in[5];
  const float* b1 = (const float*)d_in[6];
  const float* W2 = (const float*)d_in[7];
  const float* b2 = (const float*)d_in[8];
  const float* g = (const float*)d_in[9];
  const float* be = (const float*)d_in[10];
  float* out = (float*)d_out;

  // Workspace: W1p (384 KB bf16) then W2p (128 KB bf16).
  bf16* W1p = (bf16*)d_ws;
  bf16* W2p = W1p + 384 * 512;

  // Pack weights into MFMA B-fragment layout (cheap: ~1 MB read, 512 KB write).
  pack_weights<<<(384 * 512 + 255) / 256, 256, 0, stream>>>(W1, W2, W1p, W2p);

  edge_mlp_kernel<<<NBLK, 512, 0, stream>>>(srcf, dstf, edgef, sidx, didx,
                                            W1p, W2p, b1, b2, g, be, out);
}